// Round 5
// baseline (88.545 us; speedup 1.0000x reference)
//
#include <hip/hip_runtime.h>
#include <math.h>

// E=256, R=16, F=64.
// lrelu(a=0.2): lrelu(x)=0.6x+0.4|x|; softmax s>0 => lrelu(s*c*h)=s*(0.6*c*h+0.4*|c|*|h|)
// att[j,k,f] = 0.6*c*P + 0.4*|c|*Q, c=h[j,f]*r[k,f], P=sum_i s[i,j,k]h[i,f], Q with |h|.
// s[i,j,k] = exp(adj[i,j,k]-m[i,k]) * Sinv[i,k]  (stats from K1a, s materialized in LDS only)

__device__ __forceinline__ float eluf(float x) { return x > 0.f ? x : expm1f(x); }

// ---------------------------------------------------------------------------
// K1a: per (i,k): m = max_j adj[i,j,k], Sinv = 1/sum_j exp(adj-m).
// block=i (256), thread=j (256). Writes mS float2[i*16+k] (32 KB total).
// ---------------------------------------------------------------------------
__global__ __launch_bounds__(256) void k1_stats(const float* __restrict__ adj,
                                                float2* __restrict__ mS) {
  __shared__ float red[64];
  __shared__ float mk[16];
  const int b = blockIdx.x, t = threadIdx.x;
  const int lane = t & 63, wv = t >> 6;
  float v[16];
  const float4* a4 = (const float4*)(adj + b * 4096 + t * 16);
  float4 x0 = a4[0], x1 = a4[1], x2 = a4[2], x3 = a4[3];
  v[0]=x0.x; v[1]=x0.y; v[2]=x0.z; v[3]=x0.w;
  v[4]=x1.x; v[5]=x1.y; v[6]=x1.z; v[7]=x1.w;
  v[8]=x2.x; v[9]=x2.y; v[10]=x2.z; v[11]=x2.w;
  v[12]=x3.x; v[13]=x3.y; v[14]=x3.z; v[15]=x3.w;
  float m[16];
  #pragma unroll
  for (int k=0;k<16;++k) m[k]=v[k];
  #pragma unroll
  for (int off=1; off<64; off<<=1)
    #pragma unroll
    for (int k=0;k<16;++k) m[k] = fmaxf(m[k], __shfl_xor(m[k], off, 64));
  if (lane == 0) {
    #pragma unroll
    for (int k=0;k<16;++k) red[wv*16+k] = m[k];
  }
  __syncthreads();
  if (t < 16) mk[t] = fmaxf(fmaxf(red[t], red[16+t]), fmaxf(red[32+t], red[48+t]));
  __syncthreads();
  float sum[16];
  #pragma unroll
  for (int k=0;k<16;++k) sum[k] = __expf(v[k] - mk[k]);
  #pragma unroll
  for (int off=1; off<64; off<<=1)
    #pragma unroll
    for (int k=0;k<16;++k) sum[k] += __shfl_xor(sum[k], off, 64);
  __syncthreads();
  if (lane == 0) {
    #pragma unroll
    for (int k=0;k<16;++k) red[wv*16+k] = sum[k];
  }
  __syncthreads();
  if (t < 16) {
    const float S = red[t] + red[16+t] + red[32+t] + red[48+t];
    mS[b*16 + t] = make_float2(mk[t], 1.f / S);
  }
}

// ---------------------------------------------------------------------------
// K2: per j (256 blocks, 1024 threads): build s-slice in LDS from adj+stats,
// contraction -> att[j,:,:], row-softmax over k -> lin[j,:] (no aR store).
// t = [kg:2][igH:2][igL:2][fg:4]; ig = igH*4+igL owns 16 i's.
// ---------------------------------------------------------------------------
__global__ __launch_bounds__(1024) void k2_contract(const float* __restrict__ h,
                                                    const float* __restrict__ r,
                                                    const float* __restrict__ adj,
                                                    const float2* __restrict__ mS,
                                                    const float* __restrict__ w,
                                                    const float* __restrict__ bias,
                                                    float* __restrict__ att,
                                                    float* __restrict__ lin) {
  __shared__ float hl[256 * 64];        // 64 KB
  __shared__ float sl[256 * 16];        // 16 KB computed s-slice [i][k]
  __shared__ float redp[4 * 16 * 68];   // 17 KB
  __shared__ float redq[4 * 16 * 68];   // 17 KB
  __shared__ float attl[16 * 68];       // 4.3 KB
  const int j = blockIdx.x, t = threadIdx.x;
  const int lane = t & 63, wv = t >> 6;

  float4* hl4 = (float4*)hl;
  const float4* h4 = (const float4*)h;
  #pragma unroll
  for (int q=0;q<4;++q) hl4[q*1024+t] = h4[q*1024+t];
  // s-slice: thread t computes 4 consecutive values v=4t..4t+3 (same i)
  {
    const int v0 = t * 4;
    const int i = v0 >> 4, k0 = v0 & 15;
    const float4 av = *(const float4*)(adj + (size_t)i*4096 + j*16 + k0);
    const float2 m0 = mS[i*16+k0+0], m1 = mS[i*16+k0+1];
    const float2 m2 = mS[i*16+k0+2], m3 = mS[i*16+k0+3];
    float4 sv;
    sv.x = __expf(av.x - m0.x) * m0.y;
    sv.y = __expf(av.y - m1.x) * m1.y;
    sv.z = __expf(av.z - m2.x) * m2.y;
    sv.w = __expf(av.w - m3.x) * m3.y;
    *(float4*)&sl[i*16 + k0] = sv;
  }
  __syncthreads();

  const int kg = t >> 8, igH = (t >> 6) & 3, igL = (t >> 4) & 3, fg = t & 15;
  const int ig = igH*4 + igL;
  float p[4][4] = {};
  float qa[4][4] = {};
  #pragma unroll 8
  for (int ii=0; ii<16; ++ii) {
    const int i = ig*16 + ii;
    const float4 sv = *(const float4*)&sl[i*16 + kg*4];
    const float4 hv = *(const float4*)&hl[i*64 + fg*4];
    const float hvv[4] = {hv.x,hv.y,hv.z,hv.w};
    const float hav[4] = {fabsf(hv.x),fabsf(hv.y),fabsf(hv.z),fabsf(hv.w)};
    const float svv[4] = {sv.x,sv.y,sv.z,sv.w};
    #pragma unroll
    for (int kk=0;kk<4;++kk)
      #pragma unroll
      for (int ff=0;ff<4;++ff) {
        p[kk][ff]  = fmaf(svv[kk], hvv[ff], p[kk][ff]);
        qa[kk][ff] = fmaf(svv[kk], hav[ff], qa[kk][ff]);
      }
  }
  // reduce igL (lane bits 4-5)
  #pragma unroll
  for (int kk=0;kk<4;++kk)
    #pragma unroll
    for (int ff=0;ff<4;++ff) {
      p[kk][ff]  += __shfl_xor(p[kk][ff], 16, 64);
      p[kk][ff]  += __shfl_xor(p[kk][ff], 32, 64);
      qa[kk][ff] += __shfl_xor(qa[kk][ff], 16, 64);
      qa[kk][ff] += __shfl_xor(qa[kk][ff], 32, 64);
    }
  if (igL == 0) {
    #pragma unroll
    for (int kk=0;kk<4;++kk) {
      const int row = igH*16 + kg*4 + kk;
      *(float4*)&redp[row*68 + fg*4] = make_float4(p[kk][0],p[kk][1],p[kk][2],p[kk][3]);
      *(float4*)&redq[row*68 + fg*4] = make_float4(qa[kk][0],qa[kk][1],qa[kk][2],qa[kk][3]);
    }
  }
  __syncthreads();
  // finalize: thread t -> (k,f)
  {
    const int k = t >> 6, f = t & 63;
    const int o = k*68 + f;
    const float pv = redp[o] + redp[1088+o] + redp[2176+o] + redp[3264+o];
    const float qv = redq[o] + redq[1088+o] + redq[2176+o] + redq[3264+o];
    const float c = hl[j*64+f] * r[k*64+f];
    const float av = 0.6f*c*pv + 0.4f*fabsf(c)*qv;
    attl[o] = av;
    att[j*1024 + t] = av;       // t == k*64+f, coalesced
  }
  __syncthreads();
  // row softmax over k (wave wv owns k=wv; f=lane); lin only
  {
    const int f = lane;
    float mr = attl[f];
    #pragma unroll
    for (int k=1;k<16;++k) mr = fmaxf(mr, attl[k*68+f]);
    float ssum = 0.f;
    #pragma unroll
    for (int k=0;k<16;++k) ssum += __expf(attl[k*68+f]-mr);
    const float a = __expf(attl[wv*68+f]-mr) * (1.f/ssum);
    float vs = a * w[f];
    #pragma unroll
    for (int off=1; off<64; off<<=1) vs += __shfl_xor(vs, off, 64);
    if (f == 0) lin[j*16 + wv] = vs + bias[0];
  }
}

// ---------------------------------------------------------------------------
// K3: blocks 0..63: f = b; thread = e. In-register att column group:
//   v[k] = att[e,k,f]. Row softmax (over k) -> r_prime contributions;
//   col stats (over e) -> M,Sinv -> h_prime.
//   blocks 64..79: alpha row a = b-64 (softmax of 256 contiguous lin).
// ---------------------------------------------------------------------------
__global__ __launch_bounds__(256) void k3_final(const float* __restrict__ att,
                                               const float* __restrict__ lin,
                                               const float* __restrict__ h,
                                               const float* __restrict__ r,
                                               float* __restrict__ out) {
  __shared__ float red[4][17];
  __shared__ float red16[3][4][16];
  __shared__ float Mf[16], Sf[16];
  const int b = blockIdx.x, t = threadIdx.x;
  const int lane = t & 63, wv = t >> 6;
  if (b < 64) {
    const int f = b, e = t;
    float v[16];
    #pragma unroll
    for (int k=0;k<16;++k) v[k] = att[e*1024 + k*64 + f];
    // ---- col max over e (per k)
    float cm[16];
    #pragma unroll
    for (int k=0;k<16;++k) cm[k] = v[k];
    #pragma unroll
    for (int off=1; off<64; off<<=1)
      #pragma unroll
      for (int k=0;k<16;++k) cm[k] = fmaxf(cm[k], __shfl_xor(cm[k], off, 64));
    if (lane == 0) {
      #pragma unroll
      for (int k=0;k<16;++k) red16[0][wv][k] = cm[k];
    }
    // ---- row softmax over k for r_prime contribution
    float rm = v[0];
    #pragma unroll
    for (int k=1;k<16;++k) rm = fmaxf(rm, v[k]);
    float ex[16]; float rs = 0.f;
    #pragma unroll
    for (int k=0;k<16;++k) { ex[k] = __expf(v[k]-rm); rs += ex[k]; }
    const float rinv = 1.f/rs;
    #pragma unroll
    for (int k=0;k<16;++k) ex[k] *= rinv;
    #pragma unroll
    for (int off=1; off<64; off<<=1)
      #pragma unroll
      for (int k=0;k<16;++k) ex[k] += __shfl_xor(ex[k], off, 64);
    if (lane == 0) {
      #pragma unroll
      for (int k=0;k<16;++k) red16[1][wv][k] = ex[k];
    }
    __syncthreads();
    if (t < 16) {
      Mf[t] = fmaxf(fmaxf(red16[0][0][t], red16[0][1][t]),
                    fmaxf(red16[0][2][t], red16[0][3][t]));
    }
    __syncthreads();
    // ---- col sum of exp(v - M) over e (per k)
    float se[16];
    #pragma unroll
    for (int k=0;k<16;++k) se[k] = __expf(v[k] - Mf[k]);
    #pragma unroll
    for (int off=1; off<64; off<<=1)
      #pragma unroll
      for (int k=0;k<16;++k) se[k] += __shfl_xor(se[k], off, 64);
    if (lane == 0) {
      #pragma unroll
      for (int k=0;k<16;++k) red16[2][wv][k] = se[k];
    }
    __syncthreads();
    if (t < 16) {
      const float S = red16[2][0][t] + red16[2][1][t] + red16[2][2][t] + red16[2][3][t];
      Sf[t] = 1.f / S;
      const float RS = red16[1][0][t] + red16[1][1][t] + red16[1][2][t] + red16[1][3][t];
      out[16384 + t*64 + f] = eluf(r[t*64 + f] * RS);   // r_prime
    }
    __syncthreads();
    // ---- h_prime
    float hp = 0.f;
    #pragma unroll
    for (int k=0;k<16;++k) hp += __expf(v[k] - Mf[k]) * Sf[k];
    out[e*64 + f] = eluf(h[e*64 + f] * hp);
  } else {
    const int a = b - 64;
    const float lv = lin[a*256 + t];
    float m2 = lv;
    #pragma unroll
    for (int off=1; off<64; off<<=1) m2 = fmaxf(m2, __shfl_xor(m2, off, 64));
    if (lane == 0) red[wv][0] = m2;
    __syncthreads();
    m2 = fmaxf(fmaxf(red[0][0], red[1][0]), fmaxf(red[2][0], red[3][0]));
    const float ex = __expf(lv - m2);
    float ss = ex;
    #pragma unroll
    for (int off=1; off<64; off<<=1) ss += __shfl_xor(ss, off, 64);
    __syncthreads();
    if (lane == 0) red[wv][1] = ss;
    __syncthreads();
    ss = red[0][1] + red[1][1] + red[2][1] + red[3][1];
    out[17408 + a*256 + t] = ex * (1.f/ss);
  }
}

extern "C" void kernel_launch(void* const* d_in, const int* in_sizes, int n_in,
                              void* d_out, int out_size, void* d_ws, size_t ws_size,
                              hipStream_t stream) {
  (void)in_sizes; (void)n_in; (void)out_size; (void)ws_size;
  const float* h   = (const float*)d_in[0];   // (256,64)
  const float* r   = (const float*)d_in[1];   // (16,64)
  const float* adj = (const float*)d_in[2];   // (256,256,16)
  const float* w   = (const float*)d_in[3];   // (1,64)
  const float* bi  = (const float*)d_in[4];   // (1,)
  float* out = (float*)d_out;

  float* ws   = (float*)d_ws;
  float* att  = ws;                  // 262,144 f32 (1 MB)
  float* lin  = ws + 262144;         // 4,096 f32
  float2* mS  = (float2*)(ws + 266240);  // 4,096 float2 (32 KB)

  hipLaunchKernelGGL(k1_stats,    dim3(256), dim3(256),  0, stream, adj, mS);
  hipLaunchKernelGGL(k2_contract, dim3(256), dim3(1024), 0, stream, h, r, adj, mS, w, bi, att, lin);
  hipLaunchKernelGGL(k3_final,    dim3(80),  dim3(256),  0, stream, att, lin, h, r, out);
}